// Round 13
// baseline (174.562 us; speedup 1.0000x reference)
//
#include <hip/hip_runtime.h>
#include <hip/hip_bf16.h>

typedef unsigned short u16;
typedef __attribute__((ext_vector_type(8))) __bf16 bf16x8;
typedef __attribute__((ext_vector_type(4))) __bf16 bf16x4;
typedef __attribute__((ext_vector_type(4))) float f32x4;

#define LOG2E 1.44269504f

#if __has_builtin(__builtin_amdgcn_exp2f)
#define EXP2F(x) __builtin_amdgcn_exp2f(x)
#else
#define EXP2F(x) __expf((x) * 0.69314718f)
#endif

#define GLL16(gptr, lptr) \
  __builtin_amdgcn_global_load_lds((__attribute__((address_space(1))) void*)(gptr), \
                                   (__attribute__((address_space(3))) void*)(lptr), 16, 0, 0)

static __device__ __forceinline__ u16 f2bf(float f) {
  union { float f; unsigned u; } v; v.f = f;
  unsigned r = (v.u + 0x7FFFu + ((v.u >> 16) & 1u)) >> 16;
  return (u16)r;
}

// ---------------- fp32 -> bf16 convert (weights only) ----------------
__global__ __launch_bounds__(256) void cvt_w(
    const float* __restrict__ w1, const float* __restrict__ w2,
    u16* __restrict__ wq, u16* __restrict__ wp) {
  const int b = blockIdx.x;
  const float* src; u16* dst; int off;
  if (b < 3072) { src = w1; dst = wq; off = b; }
  else          { src = w2; dst = wp; off = b - 3072; }
  const int i = off * 256 + threadIdx.x;
  float4 vv = ((const float4*)src)[i];
  ushort4 o;
  o.x = f2bf(vv.x); o.y = f2bf(vv.y); o.z = f2bf(vv.z); o.w = f2bf(vv.w);
  ((ushort4*)dst)[i] = o;
}

// ---------------- QKV projection GEMM (fp32 A inputs, in-register cvt) ----------------
// C[s][f] = sum_e X[s][e] * W[f][e] + bias[f]. Q output pre-scaled by 0.125*log2e.
// A staged via reg: fp32 global load -> bf16 cvt -> ds_write (no separate cvt kernel).
__global__ __launch_bounds__(256, 2) void qkv_gemm(
    const float* __restrict__ xqf, const float* __restrict__ xkf, const float* __restrict__ xvf,
    const u16* __restrict__ wbf, const float* __restrict__ bias,
    u16* __restrict__ qout, u16* __restrict__ kout, u16* __restrict__ vtout) {
  __shared__ u16 Al[128 * 32];
  __shared__ u16 Bl[128 * 32];
  const int tid = threadIdx.x;
  const int lane = tid & 63;
  const int w = tid >> 6;
  const int wr = w >> 1, wc = w & 1;
  const int nb = blockIdx.x, mb = blockIdx.y;
  const int row0 = mb * 128;
  const int ncol0 = nb * 128;
  const int which = nb >> 3;  // 0:Q 1:K 2:V
  const float* A = (which == 0) ? xqf : (which == 1) ? xkf : xvf;
  const u16* Bw = wbf + (size_t)ncol0 * 1024;

  f32x4 acc[4][4];
  f32x4 zero = {0.f, 0.f, 0.f, 0.f};
#pragma unroll
  for (int i = 0; i < 4; i++)
#pragma unroll
    for (int j = 0; j < 4; j++) acc[i][j] = zero;

  const int srow = w * 16 + (lane >> 2);
  const int scol = (lane & 3) * 8;
  // A ds_write address: row-major [128][32], row = p*64 + srow, col = scol
  u16* Alw0 = &Al[(0 * 64 + srow) * 32 + scol];
  u16* Alw1 = &Al[(1 * 64 + srow) * 32 + scol];

  for (int k0 = 0; k0 < 1024; k0 += 32) {
    // A: reg-stage fp32 -> bf16
#pragma unroll
    for (int p = 0; p < 2; p++) {
      const float* ga = A + (size_t)(row0 + p * 64 + srow) * 1024 + k0 + scol;
      float4 a0 = *(const float4*)ga;
      float4 a1 = *(const float4*)(ga + 4);
      bf16x8 ab;
      ab[0] = (__bf16)a0.x; ab[1] = (__bf16)a0.y;
      ab[2] = (__bf16)a0.z; ab[3] = (__bf16)a0.w;
      ab[4] = (__bf16)a1.x; ab[5] = (__bf16)a1.y;
      ab[6] = (__bf16)a1.z; ab[7] = (__bf16)a1.w;
      *(bf16x8*)(p == 0 ? Alw0 : Alw1) = ab;
      const u16* gb = Bw + (size_t)(p * 64 + srow) * 1024 + k0 + scol;
      GLL16(gb, &Bl[(p * 64 + w * 16) * 32]);
    }
    __syncthreads();
    bf16x8 af[4], bfr[4];
#pragma unroll
    for (int mi = 0; mi < 4; mi++)
      af[mi] = *(const bf16x8*)&Al[(wr * 64 + mi * 16 + (lane & 15)) * 32 + (lane >> 4) * 8];
#pragma unroll
    for (int ni = 0; ni < 4; ni++)
      bfr[ni] = *(const bf16x8*)&Bl[(wc * 64 + ni * 16 + (lane & 15)) * 32 + (lane >> 4) * 8];
#pragma unroll
    for (int mi = 0; mi < 4; mi++)
#pragma unroll
      for (int ni = 0; ni < 4; ni++)
        acc[mi][ni] = __builtin_amdgcn_mfma_f32_16x16x32_bf16(af[mi], bfr[ni], acc[mi][ni], 0, 0, 0);
    __syncthreads();
  }

#pragma unroll
  for (int mi = 0; mi < 4; mi++) {
    const int rb = row0 + wr * 64 + mi * 16 + (lane >> 4) * 4;
#pragma unroll
    for (int ni = 0; ni < 4; ni++) {
      const int c = ncol0 + wc * 64 + ni * 16 + (lane & 15);
      const float bs = bias[c];
      const float sc = (which == 0) ? (0.125f * LOG2E) : 1.0f;
      const int fm = c & 1023;
      const int h = fm >> 6, d = fm & 63;
#pragma unroll
      for (int r = 0; r < 4; r++) {
        const int rr = rb + r;
        const int b = rr >> 11, s = rr & 2047;
        const u16 val = f2bf((acc[mi][ni][r] + bs) * sc);
        if (which == 0)
          qout[(((size_t)(b * 16 + h)) * 2048 + s) * 64 + d] = val;
        else if (which == 1)
          kout[(((size_t)(b * 16 + h)) * 2048 + s) * 64 + d] = val;
        else
          vtout[(((size_t)(b * 16 + h)) * 64 + d) * 2048 + s] = val;
      }
    }
  }
}

// ---------------- flash attention (round-7 structure: best measured) ----------------
// grid (bh=32, qtile=16), block 512 (8 waves x 16 q = 128 q-rows/block).
// KV tile 64, dbuf, XOR swizzle. P never goes to LDS: V's t-dim stored permuted via
//   t = pi(k): k=8g+e -> t = 32*(half) + 16*(e>>2) + 4*g + (e&3)
// so the PV B-operand is exactly the QK C-layout registers {s0,s1} / {s2,s3}.
// LDS 32KB: K buf0 [0,8192) buf1 [8192,16384); V buf0 [16384,24576) buf1 [24576,32768).

#define STAGE_KV(KOFF, VOFF)                                        \
  *(float4*)(ldsb + (KOFF) + S0) = kr0;                             \
  *(float2*)(ldsb + (VOFF) + VS0a) = make_float2(vr0.x, vr0.y);     \
  *(float2*)(ldsb + (VOFF) + VS0b) = make_float2(vr0.z, vr0.w);

#define ATTN_TILE(PAR, MC)                                                         \
  {                                                                                \
    f32x4 s0_, s1_, s2_, s3_;                                                      \
    __builtin_amdgcn_s_setprio(1);                                                 \
    {                                                                              \
      bf16x8 a_, b_;                                                               \
      a_ = *(const bf16x8*)(ldsb + Kr0 + 0 + (PAR));                               \
      b_ = *(const bf16x8*)(ldsb + Kr1 + 0 + (PAR));                               \
      s0_ = __builtin_amdgcn_mfma_f32_16x16x32_bf16(a_, q0, MC[0], 0, 0, 0);       \
      s0_ = __builtin_amdgcn_mfma_f32_16x16x32_bf16(b_, q1, s0_, 0, 0, 0);         \
      a_ = *(const bf16x8*)(ldsb + Kr0 + 2048 + (PAR));                            \
      b_ = *(const bf16x8*)(ldsb + Kr1 + 2048 + (PAR));                            \
      s1_ = __builtin_amdgcn_mfma_f32_16x16x32_bf16(a_, q0, MC[1], 0, 0, 0);       \
      s1_ = __builtin_amdgcn_mfma_f32_16x16x32_bf16(b_, q1, s1_, 0, 0, 0);         \
      a_ = *(const bf16x8*)(ldsb + Kr0 + 4096 + (PAR));                            \
      b_ = *(const bf16x8*)(ldsb + Kr1 + 4096 + (PAR));                            \
      s2_ = __builtin_amdgcn_mfma_f32_16x16x32_bf16(a_, q0, MC[2], 0, 0, 0);       \
      s2_ = __builtin_amdgcn_mfma_f32_16x16x32_bf16(b_, q1, s2_, 0, 0, 0);         \
      a_ = *(const bf16x8*)(ldsb + Kr0 + 6144 + (PAR));                            \
      b_ = *(const bf16x8*)(ldsb + Kr1 + 6144 + (PAR));                            \
      s3_ = __builtin_amdgcn_mfma_f32_16x16x32_bf16(a_, q0, MC[3], 0, 0, 0);       \
      s3_ = __builtin_amdgcn_mfma_f32_16x16x32_bf16(b_, q1, s3_, 0, 0, 0);         \
    }                                                                              \
    __builtin_amdgcn_s_setprio(0);                                                 \
    float pm = fmaxf(fmaxf(fmaxf(fmaxf(s0_[0], s0_[1]), fmaxf(s0_[2], s0_[3])),    \
                           fmaxf(fmaxf(s1_[0], s1_[1]), fmaxf(s1_[2], s1_[3]))),   \
                     fmaxf(fmaxf(fmaxf(s2_[0], s2_[1]), fmaxf(s2_[2], s2_[3])),    \
                           fmaxf(fmaxf(s3_[0], s3_[1]), fmaxf(s3_[2], s3_[3]))));  \
    /* speculative exp with current m; shfl max-reduce overlaps */                 \
    s0_[0] = EXP2F(s0_[0] - m); s0_[1] = EXP2F(s0_[1] - m);                        \
    s0_[2] = EXP2F(s0_[2] - m); s0_[3] = EXP2F(s0_[3] - m);                        \
    s1_[0] = EXP2F(s1_[0] - m); s1_[1] = EXP2F(s1_[1] - m);                        \
    s1_[2] = EXP2F(s1_[2] - m); s1_[3] = EXP2F(s1_[3] - m);                        \
    s2_[0] = EXP2F(s2_[0] - m); s2_[1] = EXP2F(s2_[1] - m);                        \
    s2_[2] = EXP2F(s2_[2] - m); s2_[3] = EXP2F(s2_[3] - m);                        \
    s3_[0] = EXP2F(s3_[0] - m); s3_[1] = EXP2F(s3_[1] - m);                        \
    s3_[2] = EXP2F(s3_[2] - m); s3_[3] = EXP2F(s3_[3] - m);                        \
    float ps = ((s0_[0] + s0_[1]) + (s0_[2] + s0_[3])) +                           \
               ((s1_[0] + s1_[1]) + (s1_[2] + s1_[3])) +                           \
               ((s2_[0] + s2_[1]) + (s2_[2] + s2_[3])) +                           \
               ((s3_[0] + s3_[1]) + (s3_[2] + s3_[3]));                            \
    pm = fmaxf(pm, __shfl_xor(pm, 16));                                            \
    pm = fmaxf(pm, __shfl_xor(pm, 32));                                            \
    if (__any(pm > m + 8.0f)) {  /* rare: fix speculation exactly */               \
      const float mn = fmaxf(m, pm);                                               \
      const float al = EXP2F(m - mn);                                              \
      m = mn; lsum *= al; ps *= al;                                                \
      s0_ *= al; s1_ *= al; s2_ *= al; s3_ *= al;                                  \
      ctx[0] *= al; ctx[1] *= al; ctx[2] *= al; ctx[3] *= al;                      \
    }                                                                              \
    lsum += ps;                                                                    \
    /* pack P directly into PV B-operands (pi-matched, no LDS round-trip) */       \
    bf16x8 pa0, pa1;                                                               \
    pa0[0] = (__bf16)s0_[0]; pa0[1] = (__bf16)s0_[1];                              \
    pa0[2] = (__bf16)s0_[2]; pa0[3] = (__bf16)s0_[3];                              \
    pa0[4] = (__bf16)s1_[0]; pa0[5] = (__bf16)s1_[1];                              \
    pa0[6] = (__bf16)s1_[2]; pa0[7] = (__bf16)s1_[3];                              \
    pa1[0] = (__bf16)s2_[0]; pa1[1] = (__bf16)s2_[1];                              \
    pa1[2] = (__bf16)s2_[2]; pa1[3] = (__bf16)s2_[3];                              \
    pa1[4] = (__bf16)s3_[0]; pa1[5] = (__bf16)s3_[1];                              \
    pa1[6] = (__bf16)s3_[2]; pa1[7] = (__bf16)s3_[3];                              \
    {                                                                              \
      bf16x8 v00 = *(const bf16x8*)(ldsb + Kr0 + 16384 + (PAR));                   \
      bf16x8 v01 = *(const bf16x8*)(ldsb + Kr1 + 16384 + (PAR));                   \
      bf16x8 v10 = *(const bf16x8*)(ldsb + Kr0 + 18432 + (PAR));                   \
      bf16x8 v11 = *(const bf16x8*)(ldsb + Kr1 + 18432 + (PAR));                   \
      bf16x8 v20 = *(const bf16x8*)(ldsb + Kr0 + 20480 + (PAR));                   \
      bf16x8 v21 = *(const bf16x8*)(ldsb + Kr1 + 20480 + (PAR));                   \
      bf16x8 v30 = *(const bf16x8*)(ldsb + Kr0 + 22528 + (PAR));                   \
      bf16x8 v31 = *(const bf16x8*)(ldsb + Kr1 + 22528 + (PAR));                   \
      __builtin_amdgcn_s_setprio(1);                                               \
      ctx[0] = __builtin_amdgcn_mfma_f32_16x16x32_bf16(v00, pa0, ctx[0], 0, 0, 0); \
      ctx[0] = __builtin_amdgcn_mfma_f32_16x16x32_bf16(v01, pa1, ctx[0], 0, 0, 0); \
      ctx[1] = __builtin_amdgcn_mfma_f32_16x16x32_bf16(v10, pa0, ctx[1], 0, 0, 0); \
      ctx[1] = __builtin_amdgcn_mfma_f32_16x16x32_bf16(v11, pa1, ctx[1], 0, 0, 0); \
      ctx[2] = __builtin_amdgcn_mfma_f32_16x16x32_bf16(v20, pa0, ctx[2], 0, 0, 0); \
      ctx[2] = __builtin_amdgcn_mfma_f32_16x16x32_bf16(v21, pa1, ctx[2], 0, 0, 0); \
      ctx[3] = __builtin_amdgcn_mfma_f32_16x16x32_bf16(v30, pa0, ctx[3], 0, 0, 0); \
      ctx[3] = __builtin_amdgcn_mfma_f32_16x16x32_bf16(v31, pa1, ctx[3], 0, 0, 0); \
      __builtin_amdgcn_s_setprio(0);                                               \
    }                                                                              \
  }

__global__ __launch_bounds__(512, 4) void attn_fwd(
    const u16* __restrict__ qbf, const u16* __restrict__ kbf, const u16* __restrict__ vtbf,
    const float* __restrict__ mask, u16* __restrict__ ctxout) {
  __shared__ u16 lds[16384];
  char* ldsb = (char*)lds;
  const int tid = threadIdx.x, lane = tid & 63, w = tid >> 6;
  const int qL = lane & 15, g = lane >> 4;
  const int x = (qL & 7) << 4;
  const int bh = blockIdx.x, qt = blockIdx.y;
  const int qbase = qt * 128;
  const size_t hbase = (size_t)bh * 2048 * 64;
  const int qrow = qbase + w * 16 + qL;

  // loop-invariant LDS byte addresses
  const int Kr0 = qL * 128 + ((g * 16) ^ x);
  const int Kr1 = qL * 128 + ((g * 16 + 64) ^ x);
  const int srow = tid >> 3;           // 0..63: full 64-row tile, 1 float4/thread
  const int scol = (tid & 7) * 8;
  const int S0 = srow * 128 + (((tid & 7) * 16) ^ ((srow & 7) << 4));
  // V staging: float4 (t=8a..8a+7) splits into 2x8B at pi-permuted offsets
  const int a_ = tid & 7;
  const int vW1 = ((a_ >> 2) << 6) + (((2 * a_) & 3) << 4) + (((a_ >> 1) & 1) << 3);
  const int vW2 = ((a_ >> 2) << 6) + (((2 * a_ + 1) & 3) << 4) + (((a_ >> 1) & 1) << 3);
  const int sxr = (srow & 7) << 4;
  const int VS0a = srow * 128 + (vW1 ^ sxr);
  const int VS0b = srow * 128 + (vW2 ^ sxr);

  // Q fragments (B-operand; pre-scaled by 0.125*log2e in qkv epilogue)
  bf16x8 q0 = *(const bf16x8*)&qbf[hbase + (size_t)qrow * 64 + g * 8];
  bf16x8 q1 = *(const bf16x8*)&qbf[hbase + (size_t)qrow * 64 + 32 + g * 8];

  // prologue: tile 0 -> LDS buf0, tile 1 -> regs
  float4 kr0, vr0;
  kr0 = *(const float4*)&kbf[hbase + (size_t)srow * 64 + scol];
  vr0 = *(const float4*)&vtbf[hbase + (size_t)srow * 2048 + scol];
  STAGE_KV(0, 16384)
  kr0 = *(const float4*)&kbf[hbase + (size_t)(64 + srow) * 64 + scol];
  vr0 = *(const float4*)&vtbf[hbase + (size_t)srow * 2048 + 64 + scol];

  // global stream pointers (tile 2 onward)
  const u16* kp = kbf + hbase + (size_t)(128 + srow) * 64 + scol;
  const u16* vp = vtbf + hbase + (size_t)srow * 2048 + 128 + scol;
  const float* mp = mask + (size_t)qrow * 2048 + g * 4;

  f32x4 mA[4], mB[4];
#pragma unroll
  for (int tb = 0; tb < 4; tb++)
    mA[tb] = (*(const f32x4*)(mp + tb * 16)) * LOG2E;

  float m = 0.f, lsum = 0.f;  // m=0 init is safe: defer-max picks up
  f32x4 ctx[4];
  f32x4 zero = {0.f, 0.f, 0.f, 0.f};
#pragma unroll
  for (int db = 0; db < 4; db++) ctx[db] = zero;

  __syncthreads();

  for (int i = 0; i < 16; ++i) {
    // ---- even tile t=2i (buffer 0) ----
    STAGE_KV(8192, 24576)                  // stage tile 2i+1 -> buf1
    if (i < 15) {                          // load tile 2i+2
      kr0 = *(const float4*)kp;
      vr0 = *(const float4*)vp;
      kp += 4096; vp += 64;
    }
#pragma unroll
    for (int tb = 0; tb < 4; tb++)         // mask for tile 2i+1
      mB[tb] = (*(const f32x4*)(mp + 64 + tb * 16)) * LOG2E;
    ATTN_TILE(0, mA)
    __syncthreads();

    // ---- odd tile t=2i+1 (buffer 1) ----
    if (i < 15) {
      STAGE_KV(0, 16384)                   // stage tile 2i+2 -> buf0
      kr0 = *(const float4*)kp;            // load tile 2i+3
      vr0 = *(const float4*)vp;
      kp += 4096; vp += 64;
#pragma unroll
      for (int tb = 0; tb < 4; tb++)       // mask for tile 2i+2
        mA[tb] = (*(const f32x4*)(mp + 128 + tb * 16)) * LOG2E;
    }
    ATTN_TILE(8192, mB)
    mp += 128;
    __syncthreads();
  }

  // finalize: reduce per-lane partial lsum across the 4 g-lane groups
  lsum += __shfl_xor(lsum, 16);
  lsum += __shfl_xor(lsum, 32);
  const float inv = 1.0f / lsum;
  const int b = bh >> 4, h = bh & 15;
  u16* orow = ctxout + (size_t)(b * 2048 + qrow) * 1024 + h * 64;
#pragma unroll
  for (int db = 0; db < 4; db++) {
    bf16x4 o;
    o[0] = (__bf16)(ctx[db][0] * inv);
    o[1] = (__bf16)(ctx[db][1] * inv);
    o[2] = (__bf16)(ctx[db][2] * inv);
    o[3] = (__bf16)(ctx[db][3] * inv);
    *(bf16x4*)&orow[db * 16 + g * 4] = o;
  }
}

// ---------------- output projection GEMM ----------------
__global__ __launch_bounds__(256, 2) void proj_gemm(
    const u16* __restrict__ ctx, const u16* __restrict__ wbf,
    const float* __restrict__ bias, float* __restrict__ out) {
  __shared__ u16 Al[128 * 32];
  __shared__ u16 Bl[128 * 32];
  const int tid = threadIdx.x;
  const int lane = tid & 63;
  const int w = tid >> 6;
  const int wr = w >> 1, wc = w & 1;
  const int nb = blockIdx.x, mb = blockIdx.y;
  const int row0 = mb * 128;
  const int ncol0 = nb * 128;
  const u16* Bw = wbf + (size_t)ncol0 * 1024;

  f32x4 acc[4][4];
  f32x4 zero = {0.f, 0.f, 0.f, 0.f};
#pragma unroll
  for (int i = 0; i < 4; i++)
#pragma unroll
    for (int j = 0; j < 4; j++) acc[i][j] = zero;

  const int srow = w * 16 + (lane >> 2);
  const int scol = (lane & 3) * 8;

  for (int k0 = 0; k0 < 1024; k0 += 32) {
#pragma unroll
    for (int p = 0; p < 2; p++) {
      const u16* ga = ctx + (size_t)(row0 + p * 64 + srow) * 1024 + k0 + scol;
      GLL16(ga, &Al[(p * 64 + w * 16) * 32]);
      const u16* gb = Bw + (size_t)(p * 64 + srow) * 1024 + k0 + scol;
      GLL16(gb, &Bl[(p * 64 + w * 16) * 32]);
    }
    __syncthreads();
    bf16x8 af[4], bfr[4];
#pragma unroll
    for (int mi = 0; mi < 4; mi++)
      af[mi] = *(const bf16x8*)&Al[(wr * 64 + mi * 16 + (lane & 15)) * 32 + (lane >> 4) * 8];
#pragma unroll
    for (int ni = 0; ni < 4; ni++)
      bfr[ni] = *(const bf16x8*)&Bl[(wc * 64 + ni * 16 + (lane & 15)) * 32 + (lane >> 4) * 8];
#pragma unroll
    for (int mi = 0; mi < 4; mi++)
#pragma unroll
      for (int ni = 0; ni < 4; ni++)
        acc[mi][ni] = __builtin_amdgcn_mfma_f32_16x16x32_bf16(af[mi], bfr[ni], acc[mi][ni], 0, 0, 0);
    __syncthreads();
  }

#pragma unroll
  for (int mi = 0; mi < 4; mi++) {
    const int rb = row0 + wr * 64 + mi * 16 + (lane >> 4) * 4;
#pragma unroll
    for (int ni = 0; ni < 4; ni++) {
      const int c = ncol0 + wc * 64 + ni * 16 + (lane & 15);
      const float bs = bias[c];
#pragma unroll
      for (int r = 0; r < 4; r++)
        out[(size_t)(rb + r) * 1024 + c] = acc[mi][ni][r] + bs;
    }
  }
}

// ---------------- launch ----------------
extern "C" void kernel_launch(void* const* d_in, const int* in_sizes, int n_in,
                              void* d_out, int out_size, void* d_ws, size_t ws_size,
                              hipStream_t stream) {
  const float* query = (const float*)d_in[0];
  const float* key   = (const float*)d_in[1];
  const float* value = (const float*)d_in[2];
  const float* qkvw  = (const float*)d_in[3];
  const float* qkvb  = (const float*)d_in[4];
  const float* projw = (const float*)d_in[5];
  const float* projb = (const float*)d_in[6];
  const float* mask  = (const float*)d_in[7];

  char* ws = (char*)d_ws;
  u16* wqkv  = (u16*)(ws + 0);          // 6 MiB  [3072][1024] bf16
  u16* wproj = (u16*)(ws + 6291456);    // 2 MiB  [1024][1024] bf16
  u16* cx    = (u16*)(ws + 8388608);    // 8 MiB  ctx [4096][1024] bf16
  u16* qb    = (u16*)(ws + 16777216);   // 8 MiB  [B,H,S,D] (pre-scaled)
  u16* kb    = (u16*)(ws + 25165824);   // 8 MiB  [B,H,S,D]
  u16* vt    = (u16*)(ws + 33554432);   // 8 MiB  [B,H,D,S]

  cvt_w<<<4096, 256, 0, stream>>>(qkvw, projw, wqkv, wproj);
  qkv_gemm<<<dim3(24, 32), 256, 0, stream>>>(query, key, value, wqkv, qkvb, qb, kb, vt);
  attn_fwd<<<dim3(32, 16), 512, 0, stream>>>(qb, kb, vt, mask, cx);
  proj_gemm<<<dim3(8, 32), 256, 0, stream>>>(cx, wproj, projb, (float*)d_out);
}

// Round 14
// 173.528 us; speedup vs baseline: 1.0060x; 1.0060x over previous
//
#include <hip/hip_runtime.h>
#include <hip/hip_bf16.h>

typedef unsigned short u16;
typedef __attribute__((ext_vector_type(8))) __bf16 bf16x8;
typedef __attribute__((ext_vector_type(4))) __bf16 bf16x4;
typedef __attribute__((ext_vector_type(4))) float f32x4;

#define LOG2E 1.44269504f

#if __has_builtin(__builtin_amdgcn_exp2f)
#define EXP2F(x) __builtin_amdgcn_exp2f(x)
#else
#define EXP2F(x) __expf((x) * 0.69314718f)
#endif

#define GLL16(gptr, lptr) \
  __builtin_amdgcn_global_load_lds((__attribute__((address_space(1))) void*)(gptr), \
                                   (__attribute__((address_space(3))) void*)(lptr), 16, 0, 0)

static __device__ __forceinline__ u16 f2bf(float f) {
  union { float f; unsigned u; } v; v.f = f;
  unsigned r = (v.u + 0x7FFFu + ((v.u >> 16) & 1u)) >> 16;
  return (u16)r;
}

// ---------------- fp32 -> bf16 convert (weights only) ----------------
__global__ __launch_bounds__(256) void cvt_w(
    const float* __restrict__ w1, const float* __restrict__ w2,
    u16* __restrict__ wq, u16* __restrict__ wp) {
  const int b = blockIdx.x;
  const float* src; u16* dst; int off;
  if (b < 3072) { src = w1; dst = wq; off = b; }
  else          { src = w2; dst = wp; off = b - 3072; }
  const int i = off * 256 + threadIdx.x;
  float4 vv = ((const float4*)src)[i];
  ushort4 o;
  o.x = f2bf(vv.x); o.y = f2bf(vv.y); o.z = f2bf(vv.z); o.w = f2bf(vv.w);
  ((ushort4*)dst)[i] = o;
}

// ---------------- QKV projection GEMM (fp32 A via global_load_lds + swizzle) ----------------
// C[s][f] = sum_e X[s][e] * W[f][e] + bias[f]. Q output pre-scaled by 0.125*log2e.
// A staged as fp32 through GLL16 into a [128][32]-f32 LDS tile (128B rows, XOR
// row-swizzle applied on the per-lane GLOBAL address — m173 pattern); fragment
// read converts fp32->bf16 in registers. B path unchanged (bf16 GLL16).
__global__ __launch_bounds__(256, 2) void qkv_gemm(
    const float* __restrict__ xqf, const float* __restrict__ xkf, const float* __restrict__ xvf,
    const u16* __restrict__ wbf, const float* __restrict__ bias,
    u16* __restrict__ qout, u16* __restrict__ kout, u16* __restrict__ vtout) {
  __shared__ float Al[4096];   // [128 rows][32 f32] = 16 KB, rows XOR-swizzled
  __shared__ u16 Bl[128 * 32]; // 8 KB
  char* Alb = (char*)Al;
  const int tid = threadIdx.x;
  const int lane = tid & 63;
  const int w = tid >> 6;
  const int wr = w >> 1, wc = w & 1;
  const int qL = lane & 15, g = lane >> 4;
  const int nb = blockIdx.x, mb = blockIdx.y;
  const int row0 = mb * 128;
  const int ncol0 = nb * 128;
  const int which = nb >> 3;  // 0:Q 1:K 2:V
  const float* A = (which == 0) ? xqf : (which == 1) ? xkf : xvf;
  const u16* Bw = wbf + (size_t)ncol0 * 1024;

  f32x4 acc[4][4];
  f32x4 zero = {0.f, 0.f, 0.f, 0.f};
#pragma unroll
  for (int i = 0; i < 4; i++)
#pragma unroll
    for (int j = 0; j < 4; j++) acc[i][j] = zero;

  const int srow = w * 16 + (lane >> 2);   // B staging row
  const int scol = (lane & 3) * 8;         // B staging col (bf16 elems)
  // A staging: idx = p*256 + tid; row = idx>>3; slot = idx&7 (16B each);
  // per-lane global byte col = (slot*16) ^ ((row&7)<<4)  [source pre-swizzle]
  const int arow_ = tid >> 3;              // row within issue p: p*32 + arow_ ... no:
  // idx>>3 = (p*256+tid)>>3 = p*32 + (tid>>3); handle inside loop.

  for (int k0 = 0; k0 < 1024; k0 += 32) {
#pragma unroll
    for (int p = 0; p < 4; p++) {
      const int row = p * 32 + (tid >> 3);
      const int slot = tid & 7;
      const char* ga = (const char*)(A + (size_t)(row0 + row) * 1024 + k0) +
                       (((slot * 16) ^ ((row & 7) << 4)));
      GLL16(ga, Alb + p * 4096 + w * 1024);
    }
#pragma unroll
    for (int p = 0; p < 2; p++) {
      const u16* gb = Bw + (size_t)(p * 64 + srow) * 1024 + k0 + scol;
      GLL16(gb, &Bl[(p * 64 + w * 16) * 32]);
    }
    __syncthreads();
    bf16x8 af[4], bfr[4];
#pragma unroll
    for (int mi = 0; mi < 4; mi++) {
      const int row = wr * 64 + mi * 16 + qL;
      const char* ar = Alb + row * 128;
      const int swz = (row & 7) << 4;
      f32x4 lo = *(const f32x4*)(ar + ((g * 32) ^ swz));
      f32x4 hi = *(const f32x4*)(ar + ((g * 32 + 16) ^ swz));
      af[mi][0] = (__bf16)lo[0]; af[mi][1] = (__bf16)lo[1];
      af[mi][2] = (__bf16)lo[2]; af[mi][3] = (__bf16)lo[3];
      af[mi][4] = (__bf16)hi[0]; af[mi][5] = (__bf16)hi[1];
      af[mi][6] = (__bf16)hi[2]; af[mi][7] = (__bf16)hi[3];
    }
#pragma unroll
    for (int ni = 0; ni < 4; ni++)
      bfr[ni] = *(const bf16x8*)&Bl[(wc * 64 + ni * 16 + qL) * 32 + g * 8];
#pragma unroll
    for (int mi = 0; mi < 4; mi++)
#pragma unroll
      for (int ni = 0; ni < 4; ni++)
        acc[mi][ni] = __builtin_amdgcn_mfma_f32_16x16x32_bf16(af[mi], bfr[ni], acc[mi][ni], 0, 0, 0);
    __syncthreads();
  }

#pragma unroll
  for (int mi = 0; mi < 4; mi++) {
    const int rb = row0 + wr * 64 + mi * 16 + (lane >> 4) * 4;
#pragma unroll
    for (int ni = 0; ni < 4; ni++) {
      const int c = ncol0 + wc * 64 + ni * 16 + (lane & 15);
      const float bs = bias[c];
      const float sc = (which == 0) ? (0.125f * LOG2E) : 1.0f;
      const int fm = c & 1023;
      const int h = fm >> 6, d = fm & 63;
#pragma unroll
      for (int r = 0; r < 4; r++) {
        const int rr = rb + r;
        const int b = rr >> 11, s = rr & 2047;
        const u16 val = f2bf((acc[mi][ni][r] + bs) * sc);
        if (which == 0)
          qout[(((size_t)(b * 16 + h)) * 2048 + s) * 64 + d] = val;
        else if (which == 1)
          kout[(((size_t)(b * 16 + h)) * 2048 + s) * 64 + d] = val;
        else
          vtout[(((size_t)(b * 16 + h)) * 64 + d) * 2048 + s] = val;
      }
    }
  }
}

// ---------------- flash attention (round-7 structure: best measured) ----------------
// grid (bh=32, qtile=16), block 512 (8 waves x 16 q = 128 q-rows/block).
// KV tile 64, dbuf, XOR swizzle. P never goes to LDS: V's t-dim stored permuted via
//   t = pi(k): k=8g+e -> t = 32*(half) + 16*(e>>2) + 4*g + (e&3)
// so the PV B-operand is exactly the QK C-layout registers {s0,s1} / {s2,s3}.
// LDS 32KB: K buf0 [0,8192) buf1 [8192,16384); V buf0 [16384,24576) buf1 [24576,32768).

#define STAGE_KV(KOFF, VOFF)                                        \
  *(float4*)(ldsb + (KOFF) + S0) = kr0;                             \
  *(float2*)(ldsb + (VOFF) + VS0a) = make_float2(vr0.x, vr0.y);     \
  *(float2*)(ldsb + (VOFF) + VS0b) = make_float2(vr0.z, vr0.w);

#define ATTN_TILE(PAR, MC)                                                         \
  {                                                                                \
    f32x4 s0_, s1_, s2_, s3_;                                                      \
    __builtin_amdgcn_s_setprio(1);                                                 \
    {                                                                              \
      bf16x8 a_, b_;                                                               \
      a_ = *(const bf16x8*)(ldsb + Kr0 + 0 + (PAR));                               \
      b_ = *(const bf16x8*)(ldsb + Kr1 + 0 + (PAR));                               \
      s0_ = __builtin_amdgcn_mfma_f32_16x16x32_bf16(a_, q0, MC[0], 0, 0, 0);       \
      s0_ = __builtin_amdgcn_mfma_f32_16x16x32_bf16(b_, q1, s0_, 0, 0, 0);         \
      a_ = *(const bf16x8*)(ldsb + Kr0 + 2048 + (PAR));                            \
      b_ = *(const bf16x8*)(ldsb + Kr1 + 2048 + (PAR));                            \
      s1_ = __builtin_amdgcn_mfma_f32_16x16x32_bf16(a_, q0, MC[1], 0, 0, 0);       \
      s1_ = __builtin_amdgcn_mfma_f32_16x16x32_bf16(b_, q1, s1_, 0, 0, 0);         \
      a_ = *(const bf16x8*)(ldsb + Kr0 + 4096 + (PAR));                            \
      b_ = *(const bf16x8*)(ldsb + Kr1 + 4096 + (PAR));                            \
      s2_ = __builtin_amdgcn_mfma_f32_16x16x32_bf16(a_, q0, MC[2], 0, 0, 0);       \
      s2_ = __builtin_amdgcn_mfma_f32_16x16x32_bf16(b_, q1, s2_, 0, 0, 0);         \
      a_ = *(const bf16x8*)(ldsb + Kr0 + 6144 + (PAR));                            \
      b_ = *(const bf16x8*)(ldsb + Kr1 + 6144 + (PAR));                            \
      s3_ = __builtin_amdgcn_mfma_f32_16x16x32_bf16(a_, q0, MC[3], 0, 0, 0);       \
      s3_ = __builtin_amdgcn_mfma_f32_16x16x32_bf16(b_, q1, s3_, 0, 0, 0);         \
    }                                                                              \
    __builtin_amdgcn_s_setprio(0);                                                 \
    float pm = fmaxf(fmaxf(fmaxf(fmaxf(s0_[0], s0_[1]), fmaxf(s0_[2], s0_[3])),    \
                           fmaxf(fmaxf(s1_[0], s1_[1]), fmaxf(s1_[2], s1_[3]))),   \
                     fmaxf(fmaxf(fmaxf(s2_[0], s2_[1]), fmaxf(s2_[2], s2_[3])),    \
                           fmaxf(fmaxf(s3_[0], s3_[1]), fmaxf(s3_[2], s3_[3]))));  \
    /* speculative exp with current m; shfl max-reduce overlaps */                 \
    s0_[0] = EXP2F(s0_[0] - m); s0_[1] = EXP2F(s0_[1] - m);                        \
    s0_[2] = EXP2F(s0_[2] - m); s0_[3] = EXP2F(s0_[3] - m);                        \
    s1_[0] = EXP2F(s1_[0] - m); s1_[1] = EXP2F(s1_[1] - m);                        \
    s1_[2] = EXP2F(s1_[2] - m); s1_[3] = EXP2F(s1_[3] - m);                        \
    s2_[0] = EXP2F(s2_[0] - m); s2_[1] = EXP2F(s2_[1] - m);                        \
    s2_[2] = EXP2F(s2_[2] - m); s2_[3] = EXP2F(s2_[3] - m);                        \
    s3_[0] = EXP2F(s3_[0] - m); s3_[1] = EXP2F(s3_[1] - m);                        \
    s3_[2] = EXP2F(s3_[2] - m); s3_[3] = EXP2F(s3_[3] - m);                        \
    float ps = ((s0_[0] + s0_[1]) + (s0_[2] + s0_[3])) +                           \
               ((s1_[0] + s1_[1]) + (s1_[2] + s1_[3])) +                           \
               ((s2_[0] + s2_[1]) + (s2_[2] + s2_[3])) +                           \
               ((s3_[0] + s3_[1]) + (s3_[2] + s3_[3]));                            \
    pm = fmaxf(pm, __shfl_xor(pm, 16));                                            \
    pm = fmaxf(pm, __shfl_xor(pm, 32));                                            \
    if (__any(pm > m + 8.0f)) {  /* rare: fix speculation exactly */               \
      const float mn = fmaxf(m, pm);                                               \
      const float al = EXP2F(m - mn);                                              \
      m = mn; lsum *= al; ps *= al;                                                \
      s0_ *= al; s1_ *= al; s2_ *= al; s3_ *= al;                                  \
      ctx[0] *= al; ctx[1] *= al; ctx[2] *= al; ctx[3] *= al;                      \
    }                                                                              \
    lsum += ps;                                                                    \
    /* pack P directly into PV B-operands (pi-matched, no LDS round-trip) */       \
    bf16x8 pa0, pa1;                                                               \
    pa0[0] = (__bf16)s0_[0]; pa0[1] = (__bf16)s0_[1];                              \
    pa0[2] = (__bf16)s0_[2]; pa0[3] = (__bf16)s0_[3];                              \
    pa0[4] = (__bf16)s1_[0]; pa0[5] = (__bf16)s1_[1];                              \
    pa0[6] = (__bf16)s1_[2]; pa0[7] = (__bf16)s1_[3];                              \
    pa1[0] = (__bf16)s2_[0]; pa1[1] = (__bf16)s2_[1];                              \
    pa1[2] = (__bf16)s2_[2]; pa1[3] = (__bf16)s2_[3];                              \
    pa1[4] = (__bf16)s3_[0]; pa1[5] = (__bf16)s3_[1];                              \
    pa1[6] = (__bf16)s3_[2]; pa1[7] = (__bf16)s3_[3];                              \
    {                                                                              \
      bf16x8 v00 = *(const bf16x8*)(ldsb + Kr0 + 16384 + (PAR));                   \
      bf16x8 v01 = *(const bf16x8*)(ldsb + Kr1 + 16384 + (PAR));                   \
      bf16x8 v10 = *(const bf16x8*)(ldsb + Kr0 + 18432 + (PAR));                   \
      bf16x8 v11 = *(const bf16x8*)(ldsb + Kr1 + 18432 + (PAR));                   \
      bf16x8 v20 = *(const bf16x8*)(ldsb + Kr0 + 20480 + (PAR));                   \
      bf16x8 v21 = *(const bf16x8*)(ldsb + Kr1 + 20480 + (PAR));                   \
      bf16x8 v30 = *(const bf16x8*)(ldsb + Kr0 + 22528 + (PAR));                   \
      bf16x8 v31 = *(const bf16x8*)(ldsb + Kr1 + 22528 + (PAR));                   \
      __builtin_amdgcn_s_setprio(1);                                               \
      ctx[0] = __builtin_amdgcn_mfma_f32_16x16x32_bf16(v00, pa0, ctx[0], 0, 0, 0); \
      ctx[0] = __builtin_amdgcn_mfma_f32_16x16x32_bf16(v01, pa1, ctx[0], 0, 0, 0); \
      ctx[1] = __builtin_amdgcn_mfma_f32_16x16x32_bf16(v10, pa0, ctx[1], 0, 0, 0); \
      ctx[1] = __builtin_amdgcn_mfma_f32_16x16x32_bf16(v11, pa1, ctx[1], 0, 0, 0); \
      ctx[2] = __builtin_amdgcn_mfma_f32_16x16x32_bf16(v20, pa0, ctx[2], 0, 0, 0); \
      ctx[2] = __builtin_amdgcn_mfma_f32_16x16x32_bf16(v21, pa1, ctx[2], 0, 0, 0); \
      ctx[3] = __builtin_amdgcn_mfma_f32_16x16x32_bf16(v30, pa0, ctx[3], 0, 0, 0); \
      ctx[3] = __builtin_amdgcn_mfma_f32_16x16x32_bf16(v31, pa1, ctx[3], 0, 0, 0); \
      __builtin_amdgcn_s_setprio(0);                                               \
    }                                                                              \
  }

__global__ __launch_bounds__(512, 4) void attn_fwd(
    const u16* __restrict__ qbf, const u16* __restrict__ kbf, const u16* __restrict__ vtbf,
    const float* __restrict__ mask, u16* __restrict__ ctxout) {
  __shared__ u16 lds[16384];
  char* ldsb = (char*)lds;
  const int tid = threadIdx.x, lane = tid & 63, w = tid >> 6;
  const int qL = lane & 15, g = lane >> 4;
  const int x = (qL & 7) << 4;
  const int bh = blockIdx.x, qt = blockIdx.y;
  const int qbase = qt * 128;
  const size_t hbase = (size_t)bh * 2048 * 64;
  const int qrow = qbase + w * 16 + qL;

  // loop-invariant LDS byte addresses
  const int Kr0 = qL * 128 + ((g * 16) ^ x);
  const int Kr1 = qL * 128 + ((g * 16 + 64) ^ x);
  const int srow = tid >> 3;           // 0..63: full 64-row tile, 1 float4/thread
  const int scol = (tid & 7) * 8;
  const int S0 = srow * 128 + (((tid & 7) * 16) ^ ((srow & 7) << 4));
  // V staging: float4 (t=8a..8a+7) splits into 2x8B at pi-permuted offsets
  const int a_ = tid & 7;
  const int vW1 = ((a_ >> 2) << 6) + (((2 * a_) & 3) << 4) + (((a_ >> 1) & 1) << 3);
  const int vW2 = ((a_ >> 2) << 6) + (((2 * a_ + 1) & 3) << 4) + (((a_ >> 1) & 1) << 3);
  const int sxr = (srow & 7) << 4;
  const int VS0a = srow * 128 + (vW1 ^ sxr);
  const int VS0b = srow * 128 + (vW2 ^ sxr);

  // Q fragments (B-operand; pre-scaled by 0.125*log2e in qkv epilogue)
  bf16x8 q0 = *(const bf16x8*)&qbf[hbase + (size_t)qrow * 64 + g * 8];
  bf16x8 q1 = *(const bf16x8*)&qbf[hbase + (size_t)qrow * 64 + 32 + g * 8];

  // prologue: tile 0 -> LDS buf0, tile 1 -> regs
  float4 kr0, vr0;
  kr0 = *(const float4*)&kbf[hbase + (size_t)srow * 64 + scol];
  vr0 = *(const float4*)&vtbf[hbase + (size_t)srow * 2048 + scol];
  STAGE_KV(0, 16384)
  kr0 = *(const float4*)&kbf[hbase + (size_t)(64 + srow) * 64 + scol];
  vr0 = *(const float4*)&vtbf[hbase + (size_t)srow * 2048 + 64 + scol];

  // global stream pointers (tile 2 onward)
  const u16* kp = kbf + hbase + (size_t)(128 + srow) * 64 + scol;
  const u16* vp = vtbf + hbase + (size_t)srow * 2048 + 128 + scol;
  const float* mp = mask + (size_t)qrow * 2048 + g * 4;

  f32x4 mA[4], mB[4];
#pragma unroll
  for (int tb = 0; tb < 4; tb++)
    mA[tb] = (*(const f32x4*)(mp + tb * 16)) * LOG2E;

  float m = 0.f, lsum = 0.f;  // m=0 init is safe: defer-max picks up
  f32x4 ctx[4];
  f32x4 zero = {0.f, 0.f, 0.f, 0.f};
#pragma unroll
  for (int db = 0; db < 4; db++) ctx[db] = zero;

  __syncthreads();

  for (int i = 0; i < 16; ++i) {
    // ---- even tile t=2i (buffer 0) ----
    STAGE_KV(8192, 24576)                  // stage tile 2i+1 -> buf1
    if (i < 15) {                          // load tile 2i+2
      kr0 = *(const float4*)kp;
      vr0 = *(const float4*)vp;
      kp += 4096; vp += 64;
    }
#pragma unroll
    for (int tb = 0; tb < 4; tb++)         // mask for tile 2i+1
      mB[tb] = (*(const f32x4*)(mp + 64 + tb * 16)) * LOG2E;
    ATTN_TILE(0, mA)
    __syncthreads();

    // ---- odd tile t=2i+1 (buffer 1) ----
    if (i < 15) {
      STAGE_KV(0, 16384)                   // stage tile 2i+2 -> buf0
      kr0 = *(const float4*)kp;            // load tile 2i+3
      vr0 = *(const float4*)vp;
      kp += 4096; vp += 64;
#pragma unroll
      for (int tb = 0; tb < 4; tb++)       // mask for tile 2i+2
        mA[tb] = (*(const f32x4*)(mp + 128 + tb * 16)) * LOG2E;
    }
    ATTN_TILE(8192, mB)
    mp += 128;
    __syncthreads();
  }

  // finalize: reduce per-lane partial lsum across the 4 g-lane groups
  lsum += __shfl_xor(lsum, 16);
  lsum += __shfl_xor(lsum, 32);
  const float inv = 1.0f / lsum;
  const int b = bh >> 4, h = bh & 15;
  u16* orow = ctxout + (size_t)(b * 2048 + qrow) * 1024 + h * 64;
#pragma unroll
  for (int db = 0; db < 4; db++) {
    bf16x4 o;
    o[0] = (__bf16)(ctx[db][0] * inv);
    o[1] = (__bf16)(ctx[db][1] * inv);
    o[2] = (__bf16)(ctx[db][2] * inv);
    o[3] = (__bf16)(ctx[db][3] * inv);
    *(bf16x4*)&orow[db * 16 + g * 4] = o;
  }
}

// ---------------- output projection GEMM ----------------
__global__ __launch_bounds__(256, 2) void proj_gemm(
    const u16* __restrict__ ctx, const u16* __restrict__ wbf,
    const float* __restrict__ bias, float* __restrict__ out) {
  __shared__ u16 Al[128 * 32];
  __shared__ u16 Bl[128 * 32];
  const int tid = threadIdx.x;
  const int lane = tid & 63;
  const int w = tid >> 6;
  const int wr = w >> 1, wc = w & 1;
  const int nb = blockIdx.x, mb = blockIdx.y;
  const int row0 = mb * 128;
  const int ncol0 = nb * 128;
  const u16* Bw = wbf + (size_t)ncol0 * 1024;

  f32x4 acc[4][4];
  f32x4 zero = {0.f, 0.f, 0.f, 0.f};
#pragma unroll
  for (int i = 0; i < 4; i++)
#pragma unroll
    for (int j = 0; j < 4; j++) acc[i][j] = zero;

  const int srow = w * 16 + (lane >> 2);
  const int scol = (lane & 3) * 8;

  for (int k0 = 0; k0 < 1024; k0 += 32) {
#pragma unroll
    for (int p = 0; p < 2; p++) {
      const u16* ga = ctx + (size_t)(row0 + p * 64 + srow) * 1024 + k0 + scol;
      GLL16(ga, &Al[(p * 64 + w * 16) * 32]);
      const u16* gb = Bw + (size_t)(p * 64 + srow) * 1024 + k0 + scol;
      GLL16(gb, &Bl[(p * 64 + w * 16) * 32]);
    }
    __syncthreads();
    bf16x8 af[4], bfr[4];
#pragma unroll
    for (int mi = 0; mi < 4; mi++)
      af[mi] = *(const bf16x8*)&Al[(wr * 64 + mi * 16 + (lane & 15)) * 32 + (lane >> 4) * 8];
#pragma unroll
    for (int ni = 0; ni < 4; ni++)
      bfr[ni] = *(const bf16x8*)&Bl[(wc * 64 + ni * 16 + (lane & 15)) * 32 + (lane >> 4) * 8];
#pragma unroll
    for (int mi = 0; mi < 4; mi++)
#pragma unroll
      for (int ni = 0; ni < 4; ni++)
        acc[mi][ni] = __builtin_amdgcn_mfma_f32_16x16x32_bf16(af[mi], bfr[ni], acc[mi][ni], 0, 0, 0);
    __syncthreads();
  }

#pragma unroll
  for (int mi = 0; mi < 4; mi++) {
    const int rb = row0 + wr * 64 + mi * 16 + (lane >> 4) * 4;
#pragma unroll
    for (int ni = 0; ni < 4; ni++) {
      const int c = ncol0 + wc * 64 + ni * 16 + (lane & 15);
      const float bs = bias[c];
#pragma unroll
      for (int r = 0; r < 4; r++)
        out[(size_t)(rb + r) * 1024 + c] = acc[mi][ni][r] + bs;
    }
  }
}

// ---------------- launch ----------------
extern "C" void kernel_launch(void* const* d_in, const int* in_sizes, int n_in,
                              void* d_out, int out_size, void* d_ws, size_t ws_size,
                              hipStream_t stream) {
  const float* query = (const float*)d_in[0];
  const float* key   = (const float*)d_in[1];
  const float* value = (const float*)d_in[2];
  const float* qkvw  = (const float*)d_in[3];
  const float* qkvb  = (const float*)d_in[4];
  const float* projw = (const float*)d_in[5];
  const float* projb = (const float*)d_in[6];
  const float* mask  = (const float*)d_in[7];

  char* ws = (char*)d_ws;
  u16* wqkv  = (u16*)(ws + 0);          // 6 MiB  [3072][1024] bf16
  u16* wproj = (u16*)(ws + 6291456);    // 2 MiB  [1024][1024] bf16
  u16* cx    = (u16*)(ws + 8388608);    // 8 MiB  ctx [4096][1024] bf16
  u16* qb    = (u16*)(ws + 16777216);   // 8 MiB  [B,H,S,D] (pre-scaled)
  u16* kb    = (u16*)(ws + 25165824);   // 8 MiB  [B,H,S,D]
  u16* vt    = (u16*)(ws + 33554432);   // 8 MiB  [B,H,D,S]

  cvt_w<<<4096, 256, 0, stream>>>(qkvw, projw, wqkv, wproj);
  qkv_gemm<<<dim3(24, 32), 256, 0, stream>>>(query, key, value, wqkv, qkvb, qb, kb, vt);
  attn_fwd<<<dim3(32, 16), 512, 0, stream>>>(qb, kb, vt, mask, cx);
  proj_gemm<<<dim3(8, 32), 256, 0, stream>>>(cx, wproj, projb, (float*)d_out);
}

// Round 15
// 160.522 us; speedup vs baseline: 1.0875x; 1.0810x over previous
//
#include <hip/hip_runtime.h>
#include <hip/hip_bf16.h>

typedef unsigned short u16;
typedef __attribute__((ext_vector_type(8))) __bf16 bf16x8;
typedef __attribute__((ext_vector_type(4))) __bf16 bf16x4;
typedef __attribute__((ext_vector_type(4))) float f32x4;

#define LOG2E 1.44269504f

#if __has_builtin(__builtin_amdgcn_exp2f)
#define EXP2F(x) __builtin_amdgcn_exp2f(x)
#else
#define EXP2F(x) __expf((x) * 0.69314718f)
#endif

#define GLL16(gptr, lptr) \
  __builtin_amdgcn_global_load_lds((__attribute__((address_space(1))) void*)(gptr), \
                                   (__attribute__((address_space(3))) void*)(lptr), 16, 0, 0)

static __device__ __forceinline__ u16 f2bf(float f) {
  union { float f; unsigned u; } v; v.f = f;
  unsigned r = (v.u + 0x7FFFu + ((v.u >> 16) & 1u)) >> 16;
  return (u16)r;
}

// ---------------- fused fp32 -> bf16 convert (5 tensors, 1 launch) ----------------
__global__ __launch_bounds__(256) void cvt_all(
    const float* __restrict__ q, const float* __restrict__ k, const float* __restrict__ v,
    const float* __restrict__ w1, const float* __restrict__ w2,
    u16* __restrict__ xq, u16* __restrict__ xk, u16* __restrict__ xv,
    u16* __restrict__ wq, u16* __restrict__ wp) {
  const int b = blockIdx.x;
  const float* src; u16* dst; int off;
  if (b < 4096)       { src = q;  dst = xq; off = b; }
  else if (b < 8192)  { src = k;  dst = xk; off = b - 4096; }
  else if (b < 12288) { src = v;  dst = xv; off = b - 8192; }
  else if (b < 15360) { src = w1; dst = wq; off = b - 12288; }
  else                { src = w2; dst = wp; off = b - 15360; }
  const int i = off * 256 + threadIdx.x;
  float4 vv = ((const float4*)src)[i];
  ushort4 o;
  o.x = f2bf(vv.x); o.y = f2bf(vv.y); o.z = f2bf(vv.z); o.w = f2bf(vv.w);
  ((ushort4*)dst)[i] = o;
}

// ---------------- QKV projection GEMM ----------------
// C[s][f] = sum_e X[s][e] * W[f][e] + bias[f]. Q output pre-scaled by 0.125*log2e.
__global__ __launch_bounds__(256, 2) void qkv_gemm(
    const u16* __restrict__ xq, const u16* __restrict__ xk, const u16* __restrict__ xv,
    const u16* __restrict__ wbf, const float* __restrict__ bias,
    u16* __restrict__ qout, u16* __restrict__ kout, u16* __restrict__ vtout) {
  __shared__ u16 Al[128 * 32];
  __shared__ u16 Bl[128 * 32];
  const int tid = threadIdx.x;
  const int lane = tid & 63;
  const int w = tid >> 6;
  const int wr = w >> 1, wc = w & 1;
  const int nb = blockIdx.x, mb = blockIdx.y;
  const int row0 = mb * 128;
  const int ncol0 = nb * 128;
  const int which = nb >> 3;  // 0:Q 1:K 2:V
  const u16* A = (which == 0) ? xq : (which == 1) ? xk : xv;
  const u16* Bw = wbf + (size_t)ncol0 * 1024;

  f32x4 acc[4][4];
  f32x4 zero = {0.f, 0.f, 0.f, 0.f};
#pragma unroll
  for (int i = 0; i < 4; i++)
#pragma unroll
    for (int j = 0; j < 4; j++) acc[i][j] = zero;

  const int srow = w * 16 + (lane >> 2);
  const int scol = (lane & 3) * 8;

  for (int k0 = 0; k0 < 1024; k0 += 32) {
#pragma unroll
    for (int p = 0; p < 2; p++) {
      const u16* ga = A + (size_t)(row0 + p * 64 + srow) * 1024 + k0 + scol;
      GLL16(ga, &Al[(p * 64 + w * 16) * 32]);
      const u16* gb = Bw + (size_t)(p * 64 + srow) * 1024 + k0 + scol;
      GLL16(gb, &Bl[(p * 64 + w * 16) * 32]);
    }
    __syncthreads();
    bf16x8 af[4], bfr[4];
#pragma unroll
    for (int mi = 0; mi < 4; mi++)
      af[mi] = *(const bf16x8*)&Al[(wr * 64 + mi * 16 + (lane & 15)) * 32 + (lane >> 4) * 8];
#pragma unroll
    for (int ni = 0; ni < 4; ni++)
      bfr[ni] = *(const bf16x8*)&Bl[(wc * 64 + ni * 16 + (lane & 15)) * 32 + (lane >> 4) * 8];
#pragma unroll
    for (int mi = 0; mi < 4; mi++)
#pragma unroll
      for (int ni = 0; ni < 4; ni++)
        acc[mi][ni] = __builtin_amdgcn_mfma_f32_16x16x32_bf16(af[mi], bfr[ni], acc[mi][ni], 0, 0, 0);
    __syncthreads();
  }

#pragma unroll
  for (int mi = 0; mi < 4; mi++) {
    const int rb = row0 + wr * 64 + mi * 16 + (lane >> 4) * 4;
#pragma unroll
    for (int ni = 0; ni < 4; ni++) {
      const int c = ncol0 + wc * 64 + ni * 16 + (lane & 15);
      const float bs = bias[c];
      const float sc = (which == 0) ? (0.125f * LOG2E) : 1.0f;
      const int fm = c & 1023;
      const int h = fm >> 6, d = fm & 63;
#pragma unroll
      for (int r = 0; r < 4; r++) {
        const int rr = rb + r;
        const int b = rr >> 11, s = rr & 2047;
        const u16 val = f2bf((acc[mi][ni][r] + bs) * sc);
        if (which == 0)
          qout[(((size_t)(b * 16 + h)) * 2048 + s) * 64 + d] = val;
        else if (which == 1)
          kout[(((size_t)(b * 16 + h)) * 2048 + s) * 64 + d] = val;
        else
          vtout[(((size_t)(b * 16 + h)) * 64 + d) * 2048 + s] = val;
      }
    }
  }
}

// ---------------- flash attention (round-7 structure + XCD-balanced swizzle) ----------------
// grid 512 (1D, bijectively remapped), block 512 (8 waves x 16 q = 128 q-rows/block).
// Swizzle: XCD x gets an 8bh x 8qt sub-grid (balanced mask/KV L2 working set).
// KV tile 64, dbuf, XOR swizzle. P never goes to LDS: V's t-dim stored permuted via
//   t = pi(k): k=8g+e -> t = 32*(half) + 16*(e>>2) + 4*g + (e&3)
// so the PV B-operand is exactly the QK C-layout registers {s0,s1} / {s2,s3}.
// LDS 32KB: K buf0 [0,8192) buf1 [8192,16384); V buf0 [16384,24576) buf1 [24576,32768).

#define STAGE_KV(KOFF, VOFF)                                        \
  *(float4*)(ldsb + (KOFF) + S0) = kr0;                             \
  *(float2*)(ldsb + (VOFF) + VS0a) = make_float2(vr0.x, vr0.y);     \
  *(float2*)(ldsb + (VOFF) + VS0b) = make_float2(vr0.z, vr0.w);

#define ATTN_TILE(PAR, MC)                                                         \
  {                                                                                \
    f32x4 s0_, s1_, s2_, s3_;                                                      \
    __builtin_amdgcn_s_setprio(1);                                                 \
    {                                                                              \
      bf16x8 a_, b_;                                                               \
      a_ = *(const bf16x8*)(ldsb + Kr0 + 0 + (PAR));                               \
      b_ = *(const bf16x8*)(ldsb + Kr1 + 0 + (PAR));                               \
      s0_ = __builtin_amdgcn_mfma_f32_16x16x32_bf16(a_, q0, MC[0], 0, 0, 0);       \
      s0_ = __builtin_amdgcn_mfma_f32_16x16x32_bf16(b_, q1, s0_, 0, 0, 0);         \
      a_ = *(const bf16x8*)(ldsb + Kr0 + 2048 + (PAR));                            \
      b_ = *(const bf16x8*)(ldsb + Kr1 + 2048 + (PAR));                            \
      s1_ = __builtin_amdgcn_mfma_f32_16x16x32_bf16(a_, q0, MC[1], 0, 0, 0);       \
      s1_ = __builtin_amdgcn_mfma_f32_16x16x32_bf16(b_, q1, s1_, 0, 0, 0);         \
      a_ = *(const bf16x8*)(ldsb + Kr0 + 4096 + (PAR));                            \
      b_ = *(const bf16x8*)(ldsb + Kr1 + 4096 + (PAR));                            \
      s2_ = __builtin_amdgcn_mfma_f32_16x16x32_bf16(a_, q0, MC[2], 0, 0, 0);       \
      s2_ = __builtin_amdgcn_mfma_f32_16x16x32_bf16(b_, q1, s2_, 0, 0, 0);         \
      a_ = *(const bf16x8*)(ldsb + Kr0 + 6144 + (PAR));                            \
      b_ = *(const bf16x8*)(ldsb + Kr1 + 6144 + (PAR));                            \
      s3_ = __builtin_amdgcn_mfma_f32_16x16x32_bf16(a_, q0, MC[3], 0, 0, 0);       \
      s3_ = __builtin_amdgcn_mfma_f32_16x16x32_bf16(b_, q1, s3_, 0, 0, 0);         \
    }                                                                              \
    __builtin_amdgcn_s_setprio(0);                                                 \
    float pm = fmaxf(fmaxf(fmaxf(fmaxf(s0_[0], s0_[1]), fmaxf(s0_[2], s0_[3])),    \
                           fmaxf(fmaxf(s1_[0], s1_[1]), fmaxf(s1_[2], s1_[3]))),   \
                     fmaxf(fmaxf(fmaxf(s2_[0], s2_[1]), fmaxf(s2_[2], s2_[3])),    \
                           fmaxf(fmaxf(s3_[0], s3_[1]), fmaxf(s3_[2], s3_[3]))));  \
    /* speculative exp with current m; shfl max-reduce overlaps */                 \
    s0_[0] = EXP2F(s0_[0] - m); s0_[1] = EXP2F(s0_[1] - m);                        \
    s0_[2] = EXP2F(s0_[2] - m); s0_[3] = EXP2F(s0_[3] - m);                        \
    s1_[0] = EXP2F(s1_[0] - m); s1_[1] = EXP2F(s1_[1] - m);                        \
    s1_[2] = EXP2F(s1_[2] - m); s1_[3] = EXP2F(s1_[3] - m);                        \
    s2_[0] = EXP2F(s2_[0] - m); s2_[1] = EXP2F(s2_[1] - m);                        \
    s2_[2] = EXP2F(s2_[2] - m); s2_[3] = EXP2F(s2_[3] - m);                        \
    s3_[0] = EXP2F(s3_[0] - m); s3_[1] = EXP2F(s3_[1] - m);                        \
    s3_[2] = EXP2F(s3_[2] - m); s3_[3] = EXP2F(s3_[3] - m);                        \
    float ps = ((s0_[0] + s0_[1]) + (s0_[2] + s0_[3])) +                           \
               ((s1_[0] + s1_[1]) + (s1_[2] + s1_[3])) +                           \
               ((s2_[0] + s2_[1]) + (s2_[2] + s2_[3])) +                           \
               ((s3_[0] + s3_[1]) + (s3_[2] + s3_[3]));                            \
    pm = fmaxf(pm, __shfl_xor(pm, 16));                                            \
    pm = fmaxf(pm, __shfl_xor(pm, 32));                                            \
    if (__any(pm > m + 8.0f)) {  /* rare: fix speculation exactly */               \
      const float mn = fmaxf(m, pm);                                               \
      const float al = EXP2F(m - mn);                                              \
      m = mn; lsum *= al; ps *= al;                                                \
      s0_ *= al; s1_ *= al; s2_ *= al; s3_ *= al;                                  \
      ctx[0] *= al; ctx[1] *= al; ctx[2] *= al; ctx[3] *= al;                      \
    }                                                                              \
    lsum += ps;                                                                    \
    /* pack P directly into PV B-operands (pi-matched, no LDS round-trip) */       \
    bf16x8 pa0, pa1;                                                               \
    pa0[0] = (__bf16)s0_[0]; pa0[1] = (__bf16)s0_[1];                              \
    pa0[2] = (__bf16)s0_[2]; pa0[3] = (__bf16)s0_[3];                              \
    pa0[4] = (__bf16)s1_[0]; pa0[5] = (__bf16)s1_[1];                              \
    pa0[6] = (__bf16)s1_[2]; pa0[7] = (__bf16)s1_[3];                              \
    pa1[0] = (__bf16)s2_[0]; pa1[1] = (__bf16)s2_[1];                              \
    pa1[2] = (__bf16)s2_[2]; pa1[3] = (__bf16)s2_[3];                              \
    pa1[4] = (__bf16)s3_[0]; pa1[5] = (__bf16)s3_[1];                              \
    pa1[6] = (__bf16)s3_[2]; pa1[7] = (__bf16)s3_[3];                              \
    {                                                                              \
      bf16x8 v00 = *(const bf16x8*)(ldsb + Kr0 + 16384 + (PAR));                   \
      bf16x8 v01 = *(const bf16x8*)(ldsb + Kr1 + 16384 + (PAR));                   \
      bf16x8 v10 = *(const bf16x8*)(ldsb + Kr0 + 18432 + (PAR));                   \
      bf16x8 v11 = *(const bf16x8*)(ldsb + Kr1 + 18432 + (PAR));                   \
      bf16x8 v20 = *(const bf16x8*)(ldsb + Kr0 + 20480 + (PAR));                   \
      bf16x8 v21 = *(const bf16x8*)(ldsb + Kr1 + 20480 + (PAR));                   \
      bf16x8 v30 = *(const bf16x8*)(ldsb + Kr0 + 22528 + (PAR));                   \
      bf16x8 v31 = *(const bf16x8*)(ldsb + Kr1 + 22528 + (PAR));                   \
      __builtin_amdgcn_s_setprio(1);                                               \
      ctx[0] = __builtin_amdgcn_mfma_f32_16x16x32_bf16(v00, pa0, ctx[0], 0, 0, 0); \
      ctx[0] = __builtin_amdgcn_mfma_f32_16x16x32_bf16(v01, pa1, ctx[0], 0, 0, 0); \
      ctx[1] = __builtin_amdgcn_mfma_f32_16x16x32_bf16(v10, pa0, ctx[1], 0, 0, 0); \
      ctx[1] = __builtin_amdgcn_mfma_f32_16x16x32_bf16(v11, pa1, ctx[1], 0, 0, 0); \
      ctx[2] = __builtin_amdgcn_mfma_f32_16x16x32_bf16(v20, pa0, ctx[2], 0, 0, 0); \
      ctx[2] = __builtin_amdgcn_mfma_f32_16x16x32_bf16(v21, pa1, ctx[2], 0, 0, 0); \
      ctx[3] = __builtin_amdgcn_mfma_f32_16x16x32_bf16(v30, pa0, ctx[3], 0, 0, 0); \
      ctx[3] = __builtin_amdgcn_mfma_f32_16x16x32_bf16(v31, pa1, ctx[3], 0, 0, 0); \
      __builtin_amdgcn_s_setprio(0);                                               \
    }                                                                              \
  }

__global__ __launch_bounds__(512, 4) void attn_fwd(
    const u16* __restrict__ qbf, const u16* __restrict__ kbf, const u16* __restrict__ vtbf,
    const float* __restrict__ mask, u16* __restrict__ ctxout) {
  __shared__ u16 lds[16384];
  char* ldsb = (char*)lds;
  const int tid = threadIdx.x, lane = tid & 63, w = tid >> 6;
  const int qL = lane & 15, g = lane >> 4;
  const int x = (qL & 7) << 4;
  // XCD-balanced bijective swizzle: XCD (orig%8) processes an 8bh x 8qt sub-grid
  const int orig = blockIdx.x;
  const int wgid = ((orig & 7) << 6) | (orig >> 3);
  const int xx = wgid >> 6, ii = wgid & 63;
  const int bh = ((xx & 3) << 3) | (ii & 7);
  const int qt = ((xx >> 2) << 3) | (ii >> 3);
  const int qbase = qt * 128;
  const size_t hbase = (size_t)bh * 2048 * 64;
  const int qrow = qbase + w * 16 + qL;

  // loop-invariant LDS byte addresses
  const int Kr0 = qL * 128 + ((g * 16) ^ x);
  const int Kr1 = qL * 128 + ((g * 16 + 64) ^ x);
  const int srow = tid >> 3;           // 0..63: full 64-row tile, 1 float4/thread
  const int scol = (tid & 7) * 8;
  const int S0 = srow * 128 + (((tid & 7) * 16) ^ ((srow & 7) << 4));
  // V staging: float4 (t=8a..8a+7) splits into 2x8B at pi-permuted offsets
  const int a_ = tid & 7;
  const int vW1 = ((a_ >> 2) << 6) + (((2 * a_) & 3) << 4) + (((a_ >> 1) & 1) << 3);
  const int vW2 = ((a_ >> 2) << 6) + (((2 * a_ + 1) & 3) << 4) + (((a_ >> 1) & 1) << 3);
  const int sxr = (srow & 7) << 4;
  const int VS0a = srow * 128 + (vW1 ^ sxr);
  const int VS0b = srow * 128 + (vW2 ^ sxr);

  // Q fragments (B-operand; pre-scaled by 0.125*log2e in qkv epilogue)
  bf16x8 q0 = *(const bf16x8*)&qbf[hbase + (size_t)qrow * 64 + g * 8];
  bf16x8 q1 = *(const bf16x8*)&qbf[hbase + (size_t)qrow * 64 + 32 + g * 8];

  // prologue: tile 0 -> LDS buf0, tile 1 -> regs
  float4 kr0, vr0;
  kr0 = *(const float4*)&kbf[hbase + (size_t)srow * 64 + scol];
  vr0 = *(const float4*)&vtbf[hbase + (size_t)srow * 2048 + scol];
  STAGE_KV(0, 16384)
  kr0 = *(const float4*)&kbf[hbase + (size_t)(64 + srow) * 64 + scol];
  vr0 = *(const float4*)&vtbf[hbase + (size_t)srow * 2048 + 64 + scol];

  // global stream pointers (tile 2 onward)
  const u16* kp = kbf + hbase + (size_t)(128 + srow) * 64 + scol;
  const u16* vp = vtbf + hbase + (size_t)srow * 2048 + 128 + scol;
  const float* mp = mask + (size_t)qrow * 2048 + g * 4;

  f32x4 mA[4], mB[4];
#pragma unroll
  for (int tb = 0; tb < 4; tb++)
    mA[tb] = (*(const f32x4*)(mp + tb * 16)) * LOG2E;

  float m = 0.f, lsum = 0.f;  // m=0 init is safe: defer-max picks up
  f32x4 ctx[4];
  f32x4 zero = {0.f, 0.f, 0.f, 0.f};
#pragma unroll
  for (int db = 0; db < 4; db++) ctx[db] = zero;

  __syncthreads();

  for (int i = 0; i < 16; ++i) {
    // ---- even tile t=2i (buffer 0) ----
    STAGE_KV(8192, 24576)                  // stage tile 2i+1 -> buf1
    if (i < 15) {                          // load tile 2i+2
      kr0 = *(const float4*)kp;
      vr0 = *(const float4*)vp;
      kp += 4096; vp += 64;
    }
#pragma unroll
    for (int tb = 0; tb < 4; tb++)         // mask for tile 2i+1
      mB[tb] = (*(const f32x4*)(mp + 64 + tb * 16)) * LOG2E;
    ATTN_TILE(0, mA)
    __syncthreads();

    // ---- odd tile t=2i+1 (buffer 1) ----
    if (i < 15) {
      STAGE_KV(0, 16384)                   // stage tile 2i+2 -> buf0
      kr0 = *(const float4*)kp;            // load tile 2i+3
      vr0 = *(const float4*)vp;
      kp += 4096; vp += 64;
#pragma unroll
      for (int tb = 0; tb < 4; tb++)       // mask for tile 2i+2
        mA[tb] = (*(const f32x4*)(mp + 128 + tb * 16)) * LOG2E;
    }
    ATTN_TILE(8192, mB)
    mp += 128;
    __syncthreads();
  }

  // finalize: reduce per-lane partial lsum across the 4 g-lane groups
  lsum += __shfl_xor(lsum, 16);
  lsum += __shfl_xor(lsum, 32);
  const float inv = 1.0f / lsum;
  const int b = bh >> 4, h = bh & 15;
  u16* orow = ctxout + (size_t)(b * 2048 + qrow) * 1024 + h * 64;
#pragma unroll
  for (int db = 0; db < 4; db++) {
    bf16x4 o;
    o[0] = (__bf16)(ctx[db][0] * inv);
    o[1] = (__bf16)(ctx[db][1] * inv);
    o[2] = (__bf16)(ctx[db][2] * inv);
    o[3] = (__bf16)(ctx[db][3] * inv);
    *(bf16x4*)&orow[db * 16 + g * 4] = o;
  }
}

// ---------------- output projection GEMM ----------------
__global__ __launch_bounds__(256, 2) void proj_gemm(
    const u16* __restrict__ ctx, const u16* __restrict__ wbf,
    const float* __restrict__ bias, float* __restrict__ out) {
  __shared__ u16 Al[128 * 32];
  __shared__ u16 Bl[128 * 32];
  const int tid = threadIdx.x;
  const int lane = tid & 63;
  const int w = tid >> 6;
  const int wr = w >> 1, wc = w & 1;
  const int nb = blockIdx.x, mb = blockIdx.y;
  const int row0 = mb * 128;
  const int ncol0 = nb * 128;
  const u16* Bw = wbf + (size_t)ncol0 * 1024;

  f32x4 acc[4][4];
  f32x4 zero = {0.f, 0.f, 0.f, 0.f};
#pragma unroll
  for (int i = 0; i < 4; i++)
#pragma unroll
    for (int j = 0; j < 4; j++) acc[i][j] = zero;

  const int srow = w * 16 + (lane >> 2);
  const int scol = (lane & 3) * 8;

  for (int k0 = 0; k0 < 1024; k0 += 32) {
#pragma unroll
    for (int p = 0; p < 2; p++) {
      const u16* ga = ctx + (size_t)(row0 + p * 64 + srow) * 1024 + k0 + scol;
      GLL16(ga, &Al[(p * 64 + w * 16) * 32]);
      const u16* gb = Bw + (size_t)(p * 64 + srow) * 1024 + k0 + scol;
      GLL16(gb, &Bl[(p * 64 + w * 16) * 32]);
    }
    __syncthreads();
    bf16x8 af[4], bfr[4];
#pragma unroll
    for (int mi = 0; mi < 4; mi++)
      af[mi] = *(const bf16x8*)&Al[(wr * 64 + mi * 16 + (lane & 15)) * 32 + (lane >> 4) * 8];
#pragma unroll
    for (int ni = 0; ni < 4; ni++)
      bfr[ni] = *(const bf16x8*)&Bl[(wc * 64 + ni * 16 + (lane & 15)) * 32 + (lane >> 4) * 8];
#pragma unroll
    for (int mi = 0; mi < 4; mi++)
#pragma unroll
      for (int ni = 0; ni < 4; ni++)
        acc[mi][ni] = __builtin_amdgcn_mfma_f32_16x16x32_bf16(af[mi], bfr[ni], acc[mi][ni], 0, 0, 0);
    __syncthreads();
  }

#pragma unroll
  for (int mi = 0; mi < 4; mi++) {
    const int rb = row0 + wr * 64 + mi * 16 + (lane >> 4) * 4;
#pragma unroll
    for (int ni = 0; ni < 4; ni++) {
      const int c = ncol0 + wc * 64 + ni * 16 + (lane & 15);
      const float bs = bias[c];
#pragma unroll
      for (int r = 0; r < 4; r++)
        out[(size_t)(rb + r) * 1024 + c] = acc[mi][ni][r] + bs;
    }
  }
}

// ---------------- launch ----------------
extern "C" void kernel_launch(void* const* d_in, const int* in_sizes, int n_in,
                              void* d_out, int out_size, void* d_ws, size_t ws_size,
                              hipStream_t stream) {
  const float* query = (const float*)d_in[0];
  const float* key   = (const float*)d_in[1];
  const float* value = (const float*)d_in[2];
  const float* qkvw  = (const float*)d_in[3];
  const float* qkvb  = (const float*)d_in[4];
  const float* projw = (const float*)d_in[5];
  const float* projb = (const float*)d_in[6];
  const float* mask  = (const float*)d_in[7];

  char* ws = (char*)d_ws;
  u16* xq    = (u16*)(ws + 0);          // 8 MiB  (later: ctx)
  u16* xk    = (u16*)(ws + 8388608);    // 8 MiB
  u16* xv    = (u16*)(ws + 16777216);   // 8 MiB
  u16* wqkv  = (u16*)(ws + 25165824);   // 6 MiB
  u16* wproj = (u16*)(ws + 31457280);   // 2 MiB
  u16* qb    = (u16*)(ws + 33554432);   // 8 MiB  [B,H,S,D] (pre-scaled)
  u16* kb    = (u16*)(ws + 41943040);   // 8 MiB  [B,H,S,D]
  u16* vt    = (u16*)(ws + 50331648);   // 8 MiB  [B,H,D,S]
  u16* cx    = xq;                      // ctx bf16, aliases xq

  cvt_all<<<16384, 256, 0, stream>>>(query, key, value, qkvw, projw, xq, xk, xv, wqkv, wproj);
  qkv_gemm<<<dim3(24, 32), 256, 0, stream>>>(xq, xk, xv, wqkv, qkvb, qb, kb, vt);
  attn_fwd<<<512, 512, 0, stream>>>(qb, kb, vt, mask, cx);
  proj_gemm<<<dim3(8, 32), 256, 0, stream>>>(cx, wproj, projb, (float*)d_out);
}